// Round 5
// baseline (16.429 us; speedup 1.0000x reference)
//
#include <hip/hip_runtime.h>

namespace {

typedef float v2f __attribute__((ext_vector_type(2)));

constexpr int B = 4096;
constexpr int F = 256;
constexpr int H = 32;
constexpr int FT = 64;      // features per block (lane -> feature, coalesced)
constexpr int NB = 8;       // batch rows per thread (8 independent chains)
constexpr int NP = NB / 2;  // float2 pairs
constexpr int GROUPS = 4;   // 256 threads / 64 lanes-of-features
constexpr int BT = GROUPS * NB;  // batch rows per block = 32
constexpr float NEG_LOG2E = -1.44269504088896340736f;
constexpr float LOG2_0P1  = -3.32192809488736234787f;  // log2(0.1)

__global__ __launch_bounds__(256, 2) void convex_kernel(
    const float* __restrict__ inputs,
    const float* __restrict__ k,
    const float* __restrict__ W1,
    const float* __restrict__ b1,
    const float* __restrict__ W2,
    const float* __restrict__ b2,
    float* __restrict__ out)
{
  const int nfb = F / FT;                // 4
  const int fb = blockIdx.x % nfb;
  const int bb = blockIdx.x / nfb;
  const int f0 = fb * FT;
  const int b0 = bb * BT;

  const int fl = threadIdx.x & 63;
  const int g  = threadIdx.x >> 6;
  const int f  = f0 + fl;

  // ---- Per-feature params -> registers (no LDS, no syncthreads). ----
  // Each thread: 32 x float4 loads, 16B aligned, L2-resident (64KB total
  // param footprint reused by all 128 batch-blocks per feature-block).
  const float kf  = k[f];
  const float b2f = b2[f];
  const float* W1f = W1 + f * 2 * H;   // [2][H], 16B-aligned (f*256B)
  const float* b1f = b1 + f * H;       // f*128B
  const float* W2f = W2 + f * H;

  float rw1[H];  // -W1[f,0,j]
  float rc[H];   // -log2e * (k[f]*W1[f,1,j] + b1[f,j])
  float rw2[H];  // W2[f,j]
#pragma unroll
  for (int q = 0; q < H / 4; ++q) {
    const float4 a  = reinterpret_cast<const float4*>(W1f)[q];      // W1[f,0,:]
    const float4 w  = reinterpret_cast<const float4*>(W1f + H)[q];  // W1[f,1,:]
    const float4 c4 = reinterpret_cast<const float4*>(b1f)[q];
    const float4 d4 = reinterpret_cast<const float4*>(W2f)[q];
    rw1[4 * q + 0] = -a.x; rw1[4 * q + 1] = -a.y;
    rw1[4 * q + 2] = -a.z; rw1[4 * q + 3] = -a.w;
    rc[4 * q + 0] = NEG_LOG2E * fmaf(kf, w.x, c4.x);
    rc[4 * q + 1] = NEG_LOG2E * fmaf(kf, w.y, c4.y);
    rc[4 * q + 2] = NEG_LOG2E * fmaf(kf, w.z, c4.z);
    rc[4 * q + 3] = NEG_LOG2E * fmaf(kf, w.w, c4.w);
    rw2[4 * q + 0] = d4.x; rw2[4 * q + 1] = d4.y;
    rw2[4 * q + 2] = d4.z; rw2[4 * q + 3] = d4.w;
  }

  // ---- Inputs: 8 rows, 8 independent sigmoid chains. ----
  v2f nav[NP], usedv[NP], accv[NP];
#pragma unroll
  for (int i = 0; i < NB; ++i) {
    const int b = b0 + g * NB + i;
    const float x = inputs[b * F + f];   // 64 lanes -> 256B contiguous
    // na2 = log2(0.1/x); reference na = ln(0.1/x) = ln2*na2 (folded into rc)
    float n = LOG2_0P1 - __builtin_amdgcn_logf(x);
    if (n != n) n = 0.0f;                // log_filter_nan: NaN (x<0) -> 0
    nav[i >> 1][i & 1]   = n;
    usedv[i >> 1][i & 1] = (x > -0.5f) ? 1.0f : 0.0f;
    accv[i >> 1][i & 1]  = 0.0f;
  }

  // ---- Register-only inner loop: 7 instr / 2 sigmoids. ----
  // w = na2*(-W1a) + (-log2e*(k*W1b+b1));  sigma = rcp(1 + 2^w)
#pragma unroll
  for (int j = 0; j < H; ++j) {
    const v2f w1v = {rw1[j], rw1[j]};
    const v2f cv  = {rc[j], rc[j]};
    const v2f w2v = {rw2[j], rw2[j]};
#pragma unroll
    for (int p = 0; p < NP; ++p) {
      const v2f z2 = __builtin_elementwise_fma(nav[p], w1v, cv);  // v_pk_fma
      v2f e;
      e.x = __builtin_amdgcn_exp2f(z2.x);
      e.y = __builtin_amdgcn_exp2f(z2.y);
      const v2f t = e + (v2f){1.0f, 1.0f};                        // v_pk_add
      v2f s;
      s.x = __builtin_amdgcn_rcpf(t.x);
      s.y = __builtin_amdgcn_rcpf(t.y);
      accv[p] = __builtin_elementwise_fma(s, w2v, accv[p]);       // v_pk_fma
    }
  }

#pragma unroll
  for (int i = 0; i < NB; ++i) {
    const int b = b0 + g * NB + i;
    out[b * F + f] = (accv[i >> 1][i & 1] + b2f) * usedv[i >> 1][i & 1];
  }
}

}  // namespace

extern "C" void kernel_launch(void* const* d_in, const int* in_sizes, int n_in,
                              void* d_out, int out_size, void* d_ws, size_t ws_size,
                              hipStream_t stream) {
  const float* inputs = (const float*)d_in[0];
  // d_in[1] = noise: unused — the reference's return value (h_out) does not
  // depend on it (h_higher/h_lower are discarded).
  const float* k  = (const float*)d_in[2];
  const float* W1 = (const float*)d_in[3];
  const float* b1 = (const float*)d_in[4];
  const float* W2 = (const float*)d_in[5];
  const float* b2 = (const float*)d_in[6];
  float* out = (float*)d_out;

  dim3 grid((F / FT) * (B / BT));   // 4 * 128 = 512 blocks (2 per CU)
  dim3 block(256);
  hipLaunchKernelGGL(convex_kernel, grid, block, 0, stream,
                     inputs, k, W1, b1, W2, b2, out);
}

// Round 6
// 14.285 us; speedup vs baseline: 1.1501x; 1.1501x over previous
//
#include <hip/hip_runtime.h>

namespace {

typedef float v2f __attribute__((ext_vector_type(2)));

constexpr int B = 4096;
constexpr int F = 256;
constexpr int H = 32;
constexpr int FT = 64;      // features per block (lane -> feature, coalesced)
constexpr int NB = 8;       // batch rows per thread (8 independent chains)
constexpr int NP = NB / 2;  // float2 pairs
constexpr int GROUPS = 4;   // 256 threads / 64 lanes-of-features
constexpr int BT = GROUPS * NB;  // batch rows per block = 32
constexpr float NEG_LOG2E = -1.44269504088896340736f;
constexpr float LOG2_0P1  = -3.32192809488736234787f;  // log2(0.1)

__global__ __launch_bounds__(256, 2) void convex_kernel(
    const float* __restrict__ inputs,
    const float* __restrict__ k,
    const float* __restrict__ W1,
    const float* __restrict__ b1,
    const float* __restrict__ W2,
    const float* __restrict__ b2,
    float* __restrict__ out)
{
  // Packed params: sP[j][fl] = { -W1[f,0,j],
  //                              -log2e*(k[f]*W1[f,1,j] + b1[f,j]),
  //                              W2[f,j], 0 }
  // Inner loop reads ONE ds_read_b128 per j (contiguous 16B/lane,
  // conflict-free) instead of three ds_read_b32.
  __shared__ float4 sP[H][FT];   // 32 KB
  __shared__ float sB2[FT];

  const int nfb = F / FT;                // 4
  const int fb = blockIdx.x % nfb;
  const int bb = blockIdx.x / nfb;
  const int f0 = fb * FT;
  const int b0 = bb * BT;

  for (int idx = threadIdx.x; idx < FT * H; idx += 256) {
    const int fl = idx >> 5;
    const int j  = idx & (H - 1);
    const int f  = f0 + fl;
    const float kf = k[f];
    float4 p;
    p.x = -W1[(f * 2 + 0) * H + j];
    p.y = NEG_LOG2E * fmaf(kf, W1[(f * 2 + 1) * H + j], b1[f * H + j]);
    p.z = W2[f * H + j];
    p.w = 0.0f;
    sP[j][fl] = p;
  }
  if (threadIdx.x < FT) sB2[threadIdx.x] = b2[f0 + threadIdx.x];
  __syncthreads();

  const int fl = threadIdx.x & 63;
  const int g  = threadIdx.x >> 6;
  const int f  = f0 + fl;
  const float b2f = sB2[fl];

  v2f nav[NP], usedv[NP], accv[NP];
#pragma unroll
  for (int i = 0; i < NB; ++i) {
    const int b = b0 + g * NB + i;
    const float x = inputs[b * F + f];   // 64 lanes -> 256B contiguous
    // na2 = log2(0.1/x); reference na = ln(0.1/x) = ln2*na2 (folded into p.y)
    float n = LOG2_0P1 - __builtin_amdgcn_logf(x);
    if (n != n) n = 0.0f;                // log_filter_nan: NaN (x<0) -> 0
    nav[i >> 1][i & 1]   = n;
    usedv[i >> 1][i & 1] = (x > -0.5f) ? 1.0f : 0.0f;
    accv[i >> 1][i & 1]  = 0.0f;
  }

  // w = na2*(-W1a) + (-log2e*(k*W1b+b1));  sigma = rcp(1 + 2^w)
#pragma unroll
  for (int j = 0; j < H; ++j) {
    const float4 p = sP[j][fl];          // ds_read_b128
    const v2f w1v = {p.x, p.x};
    const v2f cv  = {p.y, p.y};
    const v2f w2v = {p.z, p.z};
#pragma unroll
    for (int pp = 0; pp < NP; ++pp) {
      const v2f z2 = __builtin_elementwise_fma(nav[pp], w1v, cv);  // v_pk_fma
      v2f e;
      e.x = __builtin_amdgcn_exp2f(z2.x);
      e.y = __builtin_amdgcn_exp2f(z2.y);
      const v2f t = e + (v2f){1.0f, 1.0f};                         // v_pk_add
      v2f s;
      s.x = __builtin_amdgcn_rcpf(t.x);
      s.y = __builtin_amdgcn_rcpf(t.y);
      accv[pp] = __builtin_elementwise_fma(s, w2v, accv[pp]);      // v_pk_fma
    }
  }

#pragma unroll
  for (int i = 0; i < NB; ++i) {
    const int b = b0 + g * NB + i;
    out[b * F + f] = (accv[i >> 1][i & 1] + b2f) * usedv[i >> 1][i & 1];
  }
}

}  // namespace

extern "C" void kernel_launch(void* const* d_in, const int* in_sizes, int n_in,
                              void* d_out, int out_size, void* d_ws, size_t ws_size,
                              hipStream_t stream) {
  const float* inputs = (const float*)d_in[0];
  // d_in[1] = noise: unused — the reference's return value (h_out) does not
  // depend on it (h_higher/h_lower are discarded).
  const float* k  = (const float*)d_in[2];
  const float* W1 = (const float*)d_in[3];
  const float* b1 = (const float*)d_in[4];
  const float* W2 = (const float*)d_in[5];
  const float* b2 = (const float*)d_in[6];
  float* out = (float*)d_out;

  dim3 grid((F / FT) * (B / BT));   // 4 * 128 = 512 blocks (2 per CU)
  dim3 block(256);
  hipLaunchKernelGGL(convex_kernel, grid, block, 0, stream,
                     inputs, k, W1, b1, W2, b2, out);
}

// Round 7
// 13.830 us; speedup vs baseline: 1.1880x; 1.0329x over previous
//
#include <hip/hip_runtime.h>

namespace {

typedef float v2f __attribute__((ext_vector_type(2)));

constexpr int B = 4096;
constexpr int F = 256;
constexpr int H = 32;
constexpr int FT = 64;      // features per block (lane -> feature, coalesced)
constexpr int NB = 8;       // batch rows per thread (8 independent chains)
constexpr int NP = NB / 2;  // float2 pairs
constexpr int GROUPS = 4;   // 256 threads / 64 lanes-of-features
constexpr int BT = GROUPS * NB;  // batch rows per block = 32
constexpr int FTP = FT + 1;      // LDS pad -> conflict-free
constexpr float NEG_LOG2E = -1.44269504088896340736f;
constexpr float LOG2_0P1  = -3.32192809488736234787f;  // log2(0.1)

__global__ __launch_bounds__(256, 2) void convex_kernel(
    const float* __restrict__ inputs,
    const float* __restrict__ k,
    const float* __restrict__ W1,
    const float* __restrict__ b1,
    const float* __restrict__ W2,
    const float* __restrict__ b2,
    float* __restrict__ out)
{
  __shared__ float sW1a[H][FTP];  // -W1[f,0,j]
  __shared__ float sC[H][FTP];    // -log2e * (k[f]*W1[f,1,j] + b1[f,j])
  __shared__ float sW2[H][FTP];   // W2[f,j]
  __shared__ float sB2[FT];

  const int nfb = F / FT;                // 4
  const int fb = blockIdx.x % nfb;
  const int bb = blockIdx.x / nfb;
  const int f0 = fb * FT;
  const int b0 = bb * BT;

  // Stage & pre-fold params (tiny: 6K floats, L2/L3-resident).
  for (int idx = threadIdx.x; idx < FT * H; idx += 256) {
    const int fl = idx >> 5;
    const int j  = idx & (H - 1);
    const int f  = f0 + fl;
    const float kf = k[f];
    sW1a[j][fl] = -W1[(f * 2 + 0) * H + j];
    sC[j][fl]   = NEG_LOG2E * fmaf(kf, W1[(f * 2 + 1) * H + j], b1[f * H + j]);
    sW2[j][fl]  = W2[f * H + j];
  }
  if (threadIdx.x < FT) sB2[threadIdx.x] = b2[f0 + threadIdx.x];
  __syncthreads();

  const int fl = threadIdx.x & 63;
  const int g  = threadIdx.x >> 6;
  const int f  = f0 + fl;
  const float b2f = sB2[fl];

  v2f nav[NP], usedv[NP], accv[NP];
#pragma unroll
  for (int i = 0; i < NB; ++i) {
    const int b = b0 + g * NB + i;
    const float x = inputs[b * F + f];     // 64 lanes -> 256B contiguous
    // na2 = log2(0.1/x); reference na = ln(0.1/x) = ln2 * na2 (folded into sC)
    float n = LOG2_0P1 - __builtin_amdgcn_logf(x);
    if (n != n) n = 0.0f;                  // log_filter_nan: NaN (x<0) -> 0
    nav[i >> 1][i & 1]  = n;
    usedv[i >> 1][i & 1] = (x > -0.5f) ? 1.0f : 0.0f;
    accv[i >> 1][i & 1] = 0.0f;
  }

  // z2 = na2*(-W1a) + (-log2e*(k*W1b+b1)); sigmoid = rcp(1 + 2^z2)
#pragma unroll
  for (int j = 0; j < H; ++j) {
    const float w1 = sW1a[j][fl];
    const float c  = sC[j][fl];
    const float w2 = sW2[j][fl];
    const v2f w1v = {w1, w1};
    const v2f cv  = {c, c};
    const v2f w2v = {w2, w2};
#pragma unroll
    for (int p = 0; p < NP; ++p) {
      v2f z2 = __builtin_elementwise_fma(nav[p], w1v, cv);  // v_pk_fma_f32
      v2f e;
      e.x = __builtin_amdgcn_exp2f(z2.x);
      e.y = __builtin_amdgcn_exp2f(z2.y);
      v2f t = e + (v2f){1.0f, 1.0f};                        // v_pk_add_f32
      v2f s;
      s.x = __builtin_amdgcn_rcpf(t.x);
      s.y = __builtin_amdgcn_rcpf(t.y);
      accv[p] = __builtin_elementwise_fma(s, w2v, accv[p]); // v_pk_fma_f32
    }
  }

#pragma unroll
  for (int i = 0; i < NB; ++i) {
    const int b = b0 + g * NB + i;
    out[b * F + f] = (accv[i >> 1][i & 1] + b2f) * usedv[i >> 1][i & 1];
  }
}

}  // namespace

extern "C" void kernel_launch(void* const* d_in, const int* in_sizes, int n_in,
                              void* d_out, int out_size, void* d_ws, size_t ws_size,
                              hipStream_t stream) {
  const float* inputs = (const float*)d_in[0];
  // d_in[1] = noise: unused — the reference's return value (h_out) does not
  // depend on it (h_higher/h_lower are discarded).
  const float* k  = (const float*)d_in[2];
  const float* W1 = (const float*)d_in[3];
  const float* b1 = (const float*)d_in[4];
  const float* W2 = (const float*)d_in[5];
  const float* b2 = (const float*)d_in[6];
  float* out = (float*)d_out;

  dim3 grid((F / FT) * (B / BT));   // 4 * 128 = 512 blocks (2 per CU)
  dim3 block(256);
  hipLaunchKernelGGL(convex_kernel, grid, block, 0, stream,
                     inputs, k, W1, b1, W2, b2, out);
}